// Round 1
// baseline (583.398 us; speedup 1.0000x reference)
//
#include <hip/hip_runtime.h>
#include <math.h>

#define NF 8
#define NQ 300
#define HSZ 96
#define WSZ 96
#define HW (HSZ*WSZ)        // 9216
#define DTOT (NF*HW)        // 73728
#define NT 256

// ws layout (floats)
#define WS_TGTY 0           // [2][768]  max over h, indexed [b][f*96+w]
#define WS_TGTX 1536        // [2][768]  max over w, indexed [b][f*96+h]
#define WS_TSUM 3072        // [2] sum of tmask
#define WS_YSUM 3074        // [2] sum of tgtY
#define WS_XSUM 3076        // [2] sum of tgtX

__device__ __forceinline__ float sigmoidf_(float x) {
    float e = expf(-fabsf(x));
    float inv = 1.f / (1.f + e);
    return x >= 0.f ? inv : e * inv;
}

__device__ __forceinline__ float blockSum(float v, float* red) {
    #pragma unroll
    for (int off = 32; off > 0; off >>= 1) v += __shfl_down(v, off, 64);
    int wid = threadIdx.x >> 6, lane = threadIdx.x & 63;
    __syncthreads();
    if (lane == 0) red[wid] = v;
    __syncthreads();
    return red[0] + red[1] + red[2] + red[3];
}

__global__ __launch_bounds__(NT)
void targets_kernel(const float* __restrict__ tm, float* __restrict__ ws) {
    int b = blockIdx.x, t = threadIdx.x;
    __shared__ float red[4];
    float tsum = 0.f, ysum = 0.f, xsum = 0.f;
    #pragma unroll
    for (int i = 0; i < 3; ++i) {
        int col = t + NT * i;            // 0..767
        int f = col / 96, idx = col - f * 96;
        const float* base = tm + (size_t)(b * NF + f) * HW;
        // column max (tgtY: max over h, fixed w=idx) + full sum
        float m = -INFINITY, ss = 0.f;
        for (int h = 0; h < HSZ; ++h) {
            float v = base[h * WSZ + idx];
            m = fmaxf(m, v); ss += v;
        }
        ws[WS_TGTY + b * 768 + col] = m;
        ysum += m; tsum += ss;
        // row max (tgtX: max over w, fixed h=idx)
        float mr = -INFINITY;
        for (int w2 = 0; w2 < WSZ; ++w2) mr = fmaxf(mr, base[idx * WSZ + w2]);
        ws[WS_TGTX + b * 768 + col] = mr;
        xsum += mr;
    }
    tsum = blockSum(tsum, red);
    ysum = blockSum(ysum, red);
    xsum = blockSum(xsum, red);
    if (t == 0) {
        ws[WS_TSUM + b] = tsum;
        ws[WS_YSUM + b] = ysum;
        ws[WS_XSUM + b] = xsum;
    }
}

__global__ __launch_bounds__(NT)
void cost_kernel(const float* __restrict__ logits, const float* __restrict__ boxes,
                 const float* __restrict__ masks, const float* __restrict__ tmask,
                 const float* __restrict__ tbox, const int* __restrict__ tvalid,
                 const unsigned char* __restrict__ vpad, const float* __restrict__ ws,
                 float* __restrict__ out) {
    int blk = blockIdx.x;
    int b = blk / NQ, q = blk - b * NQ;
    int t = threadIdx.x;
    __shared__ float tile[HSZ * 97];
    __shared__ float red[4];

    // valid_pad bits (independent of f): bit per iteration
    unsigned long long padbits = 0ull;
    #pragma unroll
    for (int it = 0; it < 36; ++it) {
        int e = it * NT + t;
        if (vpad[b * HW + e]) padbits |= (1ull << it);
    }

    float focal = 0.f, dnum = 0.f, dden = 0.f;
    float pYn = 0.f, pYd = 0.f, pXn = 0.f, pXd = 0.f;

    for (int f = 0; f < NF; ++f) {
        const float* mbase = masks + (size_t)((b * NF + f) * NQ + q) * HW;
        const float* tbase = tmask + (size_t)(b * NF + f) * HW;
        #pragma unroll 4
        for (int it = 0; it < 36; ++it) {
            int e = it * NT + t;
            float x = mbase[e];
            if ((padbits >> it) & 1ull) x = 0.f;
            float tv = tbase[e];
            float ax = fabsf(x);
            float ee = expf(-ax);
            float inv = 1.f / (1.f + ee);
            float s = x >= 0.f ? inv : ee * inv;       // sigmoid(x)
            float ce = fmaxf(x, 0.f) - x * tv + log1pf(ee);
            float pt = s * tv + (1.f - s) * (1.f - tv);
            float at = 0.25f * tv + 0.75f * (1.f - tv);
            float omp = 1.f - pt;
            focal += at * ce * omp * omp;
            dnum += s * tv;
            dden += s;
            int h = e / 96;
            tile[e + h] = x;                           // stride-97 padded tile
        }
        __syncthreads();
        if (t < 96) {
            // column max over h, fixed w=t  -> src_y[f][t]
            float m = -INFINITY;
            #pragma unroll 8
            for (int h = 0; h < HSZ; ++h) m = fmaxf(m, tile[h * 97 + t]);
            float sg = sigmoidf_(m);
            pYd += sg;
            pYn += sg * ws[WS_TGTY + b * 768 + f * 96 + t];
        } else if (t < 192) {
            // row max over w, fixed h  -> src_x[f][h]
            int hh = t - 96;
            float m = -INFINITY;
            #pragma unroll 8
            for (int w = 0; w < WSZ; ++w) m = fmaxf(m, tile[hh * 97 + w]);
            float sg = sigmoidf_(m);
            pXd += sg;
            pXn += sg * ws[WS_TGTX + b * 768 + f * 96 + hh];
        }
        __syncthreads();
    }

    focal = blockSum(focal, red);
    dnum  = blockSum(dnum, red);
    dden  = blockSum(dden, red);
    pYn   = blockSum(pYn, red);
    pYd   = blockSum(pYd, red);
    pXn   = blockSum(pXn, red);
    pXd   = blockSum(pXd, red);

    if (t == 0) {
        float tsum = ws[WS_TSUM + b];
        float ysum = ws[WS_YSUM + b];
        float xsum = ws[WS_XSUM + b];
        float cost_mask = focal / (float)DTOT;
        float cost_dice = -(2.f * dnum + 1.f) / (dden + tsum + 1.f);
        float coefY = (2.f * pYn + 1.f) / (pYd + ysum + 1.f);
        float coefX = (2.f * pXn + 1.f) / (pXd + xsum + 1.f);
        float cost_proj = -0.5f * (coefY + coefX);

        float wsum = 0.f, cls = 0.f, cb = 0.f, cg = 0.f;
        #pragma unroll
        for (int f = 0; f < NF; ++f) {
            float wv = (tvalid[b * NF + f] != 0) ? 1.f : 0.f;
            wsum += wv;
            float lg = logits[(b * NF + f) * NQ + q];
            float p = sigmoidf_(lg);
            float negc = 0.75f * p * p * (-logf(1.f - p + 1e-8f));
            float posc = 0.25f * (1.f - p) * (1.f - p) * (-logf(p + 1e-8f));
            cls += (posc - negc) * wv;

            const float* bx = boxes + (size_t)((b * NF + f) * NQ + q) * 4;
            const float* tb = tbox + (b * NF + f) * 4;
            float cx = bx[0], cy = bx[1], bw = bx[2], bh = bx[3];
            float tcx = tb[0], tcy = tb[1], tbw = tb[2], tbh = tb[3];
            cb += fabsf(cx - tcx) + fabsf(cy - tcy) + fabsf(bw - tbw) + fabsf(bh - tbh);
            float sx1 = cx - 0.5f * bw, sy1 = cy - 0.5f * bh;
            float sx2 = cx + 0.5f * bw, sy2 = cy + 0.5f * bh;
            float tx1 = tcx - 0.5f * tbw, ty1 = tcy - 0.5f * tbh;
            float tx2 = tcx + 0.5f * tbw, ty2 = tcy + 0.5f * tbh;
            float a1 = (sx2 - sx1) * (sy2 - sy1), a2 = (tx2 - tx1) * (ty2 - ty1);
            float iw = fmaxf(fminf(sx2, tx2) - fmaxf(sx1, tx1), 0.f);
            float ih = fmaxf(fminf(sy2, ty2) - fmaxf(sy1, ty1), 0.f);
            float inter = iw * ih;
            float uni = a1 + a2 - inter;
            float iou = inter / uni;
            float cw = fmaxf(fmaxf(sx2, tx2) - fminf(sx1, tx1), 0.f);
            float chh = fmaxf(fmaxf(sy2, ty2) - fminf(sy1, ty1), 0.f);
            float areac = cw * chh;
            cg += -(iou - (areac - uni) / areac);
        }
        cls /= wsum;
        cb *= 0.125f;
        cg *= 0.125f;
        out[b * NQ + q] = cls + cb + cg + cost_mask + cost_dice + cost_proj;
    }
}

__global__ __launch_bounds__(NT)
void argmin_kernel(float* __restrict__ out, int write_idx) {
    int b = blockIdx.x, t = threadIdx.x;
    float best = INFINITY;
    int bi = 0x7fffffff;
    for (int q = t; q < NQ; q += NT) {
        float v = out[b * NQ + q];
        if (v < best) { best = v; bi = q; }
    }
    #pragma unroll
    for (int off = 32; off > 0; off >>= 1) {
        float ov = __shfl_down(best, off, 64);
        int oi = __shfl_down(bi, off, 64);
        if (ov < best || (ov == best && oi < bi)) { best = ov; bi = oi; }
    }
    __shared__ float rv[4];
    __shared__ int ri[4];
    int wid = t >> 6, lane = t & 63;
    if (lane == 0) { rv[wid] = best; ri[wid] = bi; }
    __syncthreads();
    if (t == 0 && write_idx) {
        #pragma unroll
        for (int w = 1; w < 4; ++w) {
            if (rv[w] < best || (rv[w] == best && ri[w] < bi)) { best = rv[w]; bi = ri[w]; }
        }
        out[2 * NQ + b] = (float)bi;       // src_ind
        out[2 * NQ + 2 + b] = 0.f;         // tgt_ind
    }
}

extern "C" void kernel_launch(void* const* d_in, const int* in_sizes, int n_in,
                              void* d_out, int out_size, void* d_ws, size_t ws_size,
                              hipStream_t stream) {
    const float* logits = (const float*)d_in[0];
    const float* boxes  = (const float*)d_in[1];
    const float* masks  = (const float*)d_in[2];
    const float* tmask  = (const float*)d_in[3];
    const float* tbox   = (const float*)d_in[4];
    const int*   tvalid = (const int*)d_in[5];
    const unsigned char* vpad = (const unsigned char*)d_in[6];
    float* out = (float*)d_out;
    float* ws  = (float*)d_ws;

    targets_kernel<<<2, NT, 0, stream>>>(tmask, ws);
    cost_kernel<<<2 * NQ, NT, 0, stream>>>(logits, boxes, masks, tmask, tbox,
                                           tvalid, vpad, ws, out);
    int write_idx = (out_size >= 2 * NQ + 4) ? 1 : 0;
    argmin_kernel<<<2, NT, 0, stream>>>(out, write_idx);
}

// Round 2
// 311.822 us; speedup vs baseline: 1.8709x; 1.8709x over previous
//
#include <hip/hip_runtime.h>
#include <math.h>

#define NF 8
#define NQ 300
#define HSZ 96
#define WSZ 96
#define HW (HSZ*WSZ)        // 9216
#define DTOT (NF*HW)        // 73728
#define NT 256
#define NBF 16              // bs*NF

// ws layout (floats)
#define WS_TGTY 0            // [16][96]  max over h, indexed [bf][w]
#define WS_TGTX 1536         // [16][96]  max over w, indexed [bf][h]
#define WS_TSUM 3072         // [16] per-(b,f) sum of tmask
#define WS_YSUM 3088         // [16] per-(b,f) sum of tgtY
#define WS_XSUM 3104         // [16] per-(b,f) sum of tgtX
#define WS_PART 4096         // [4800][8] partials: focal,dnum,dden,pYn,pYd,pXn,pXd,-

__device__ __forceinline__ float sigmoid_fast(float x) {
    float e = __expf(-fabsf(x));
    float inv = __builtin_amdgcn_rcpf(1.f + e);
    return x >= 0.f ? inv : e * inv;
}

__device__ __forceinline__ float blockSum(float v, float* red) {
    #pragma unroll
    for (int off = 32; off > 0; off >>= 1) v += __shfl_down(v, off, 64);
    int wid = threadIdx.x >> 6, lane = threadIdx.x & 63;
    __syncthreads();
    if (lane == 0) red[wid] = v;
    __syncthreads();
    return red[0] + red[1] + red[2] + red[3];
}

// one block per (b,f): projections of target masks + sums
__global__ __launch_bounds__(NT)
void targets_kernel(const float* __restrict__ tm, float* __restrict__ ws) {
    int bf = blockIdx.x, t = threadIdx.x;
    __shared__ float tile[HSZ * 97];
    __shared__ float red[4];
    const float* base = tm + (size_t)bf * HW;
    float tsum = 0.f;
    #pragma unroll
    for (int it = 0; it < 36; ++it) {
        int e = it * NT + t;
        float v = base[e];
        tsum += v;
        tile[e + e / 96] = v;        // stride-97 padded
    }
    __syncthreads();
    float ysum = 0.f, xsum = 0.f;
    if (t < 96) {
        float m = -INFINITY;
        #pragma unroll 8
        for (int h = 0; h < HSZ; ++h) m = fmaxf(m, tile[h * 97 + t]);
        ws[WS_TGTY + bf * 96 + t] = m;
        ysum = m;
    } else if (t < 192) {
        int hh = t - 96;
        float m = -INFINITY;
        #pragma unroll 8
        for (int w = 0; w < WSZ; ++w) m = fmaxf(m, tile[hh * 97 + w]);
        ws[WS_TGTX + bf * 96 + hh] = m;
        xsum = m;
    }
    tsum = blockSum(tsum, red);
    ysum = blockSum(ysum, red);
    xsum = blockSum(xsum, red);
    if (t == 0) {
        ws[WS_TSUM + bf] = tsum;
        ws[WS_YSUM + bf] = ysum;
        ws[WS_XSUM + bf] = xsum;
    }
}

// one block per (b,f,q): focal/dice/projection partials over one 96x96 plane
__global__ __launch_bounds__(NT, 8)
void partial_kernel(const float* __restrict__ masks, const float* __restrict__ tmask,
                    const unsigned char* __restrict__ vpad, const float* __restrict__ ws,
                    float* __restrict__ part) {
    int bf = blockIdx.x / NQ;
    int q  = blockIdx.x - bf * NQ;
    int b  = bf >> 3;
    int t  = threadIdx.x;

    __shared__ unsigned short tile[HSZ * 98];   // bf16 (truncated), stride-98
    __shared__ float red[4];

    const float4* mrow = (const float4*)(masks + (size_t)(bf * NQ + q) * HW);
    const float4* trow = (const float4*)(tmask + (size_t)bf * HW);
    const unsigned* prow = (const unsigned*)(vpad + (size_t)b * HW);

    float focal = 0.f, dnum = 0.f, dden = 0.f;

    #pragma unroll
    for (int it = 0; it < 9; ++it) {
        int i4 = it * NT + t;            // float4 index, 0..2303
        float4 xv = mrow[i4];
        float4 tv = trow[i4];
        unsigned pv = prow[i4];
        int h = i4 / 24;                 // 4|96 -> whole float4 in one row
        int c = (i4 - h * 24) * 4;

        float xs[4] = {xv.x, xv.y, xv.z, xv.w};
        float ts[4] = {tv.x, tv.y, tv.z, tv.w};
        unsigned short us[4];
        #pragma unroll
        for (int j = 0; j < 4; ++j) {
            float x = ((pv >> (8 * j)) & 0xFFu) ? 0.f : xs[j];
            float tg = ts[j];
            float ee = __expf(-fabsf(x));
            float se = 1.f + ee;
            float inv = __builtin_amdgcn_rcpf(se);
            float s = x >= 0.f ? inv : ee * inv;          // sigmoid(x)
            float L = __logf(se);                          // log1p(exp(-|x|))
            float ce = fmaxf(x, 0.f) - x * tg + L;
            float omp = s + tg - 2.f * s * tg;             // 1 - p_t
            float at = 0.75f - 0.5f * tg;                  // alpha_t
            focal = fmaf(at * ce, omp * omp, focal);
            dnum = fmaf(s, tg, dnum);
            dden += s;
            us[j] = (unsigned short)(__float_as_uint(x) >> 16);  // bf16 trunc (monotone)
        }
        int ta = h * 98 + c;                               // even
        *(unsigned*)&tile[ta]     = (unsigned)us[0] | ((unsigned)us[1] << 16);
        *(unsigned*)&tile[ta + 2] = (unsigned)us[2] | ((unsigned)us[3] << 16);
    }
    __syncthreads();

    float pYn = 0.f, pYd = 0.f, pXn = 0.f, pXd = 0.f;
    if (t < 96) {
        float m = -INFINITY;
        #pragma unroll 8
        for (int h = 0; h < HSZ; ++h)
            m = fmaxf(m, __uint_as_float((unsigned)tile[h * 98 + t] << 16));
        float sg = sigmoid_fast(m);
        pYd = sg;
        pYn = sg * ws[WS_TGTY + bf * 96 + t];
    } else if (t < 192) {
        int hh = t - 96;
        float m = -INFINITY;
        #pragma unroll 8
        for (int w = 0; w < WSZ; ++w)
            m = fmaxf(m, __uint_as_float((unsigned)tile[hh * 98 + w] << 16));
        float sg = sigmoid_fast(m);
        pXd = sg;
        pXn = sg * ws[WS_TGTX + bf * 96 + hh];
    }

    focal = blockSum(focal, red);
    dnum  = blockSum(dnum, red);
    dden  = blockSum(dden, red);
    pYn   = blockSum(pYn, red);
    pYd   = blockSum(pYd, red);
    pXn   = blockSum(pXn, red);
    pXd   = blockSum(pXd, red);

    if (t == 0) {
        float* p = part + (size_t)blockIdx.x * 8;
        p[0] = focal; p[1] = dnum; p[2] = dden;
        p[3] = pYn;   p[4] = pYd;  p[5] = pXn;  p[6] = pXd;
    }
}

// one thread per (b,q): combine partials + class/bbox/giou
__global__ __launch_bounds__(NT)
void combine_kernel(const float* __restrict__ logits, const float* __restrict__ boxes,
                    const float* __restrict__ tbox, const int* __restrict__ tvalid,
                    const float* __restrict__ ws, float* __restrict__ out) {
    int gid = blockIdx.x * NT + threadIdx.x;
    if (gid >= 2 * NQ) return;
    int b = gid / NQ, q = gid - b * NQ;

    float focal = 0.f, dnum = 0.f, dden = 0.f;
    float pYn = 0.f, pYd = 0.f, pXn = 0.f, pXd = 0.f;
    float tsum = 0.f, ysum = 0.f, xsum = 0.f;
    #pragma unroll
    for (int f = 0; f < NF; ++f) {
        int bf = b * NF + f;
        const float* p = ws + WS_PART + (size_t)(bf * NQ + q) * 8;
        focal += p[0]; dnum += p[1]; dden += p[2];
        pYn += p[3]; pYd += p[4]; pXn += p[5]; pXd += p[6];
        tsum += ws[WS_TSUM + bf];
        ysum += ws[WS_YSUM + bf];
        xsum += ws[WS_XSUM + bf];
    }
    float cost_mask = focal / (float)DTOT;
    float cost_dice = -(2.f * dnum + 1.f) / (dden + tsum + 1.f);
    float coefY = (2.f * pYn + 1.f) / (pYd + ysum + 1.f);
    float coefX = (2.f * pXn + 1.f) / (pXd + xsum + 1.f);
    float cost_proj = -0.5f * (coefY + coefX);

    float wsum = 0.f, cls = 0.f, cb = 0.f, cg = 0.f;
    #pragma unroll
    for (int f = 0; f < NF; ++f) {
        float wv = (tvalid[b * NF + f] != 0) ? 1.f : 0.f;
        wsum += wv;
        float lg = logits[(b * NF + f) * NQ + q];
        float p = sigmoid_fast(lg);
        float negc = 0.75f * p * p * (-__logf(1.f - p + 1e-8f));
        float posc = 0.25f * (1.f - p) * (1.f - p) * (-__logf(p + 1e-8f));
        cls += (posc - negc) * wv;

        const float* bx = boxes + (size_t)((b * NF + f) * NQ + q) * 4;
        const float* tb = tbox + (b * NF + f) * 4;
        float cx = bx[0], cy = bx[1], bw = bx[2], bh = bx[3];
        float tcx = tb[0], tcy = tb[1], tbw = tb[2], tbh = tb[3];
        cb += fabsf(cx - tcx) + fabsf(cy - tcy) + fabsf(bw - tbw) + fabsf(bh - tbh);
        float sx1 = cx - 0.5f * bw, sy1 = cy - 0.5f * bh;
        float sx2 = cx + 0.5f * bw, sy2 = cy + 0.5f * bh;
        float tx1 = tcx - 0.5f * tbw, ty1 = tcy - 0.5f * tbh;
        float tx2 = tcx + 0.5f * tbw, ty2 = tcy + 0.5f * tbh;
        float a1 = (sx2 - sx1) * (sy2 - sy1), a2 = (tx2 - tx1) * (ty2 - ty1);
        float iw = fmaxf(fminf(sx2, tx2) - fmaxf(sx1, tx1), 0.f);
        float ih = fmaxf(fminf(sy2, ty2) - fmaxf(sy1, ty1), 0.f);
        float inter = iw * ih;
        float uni = a1 + a2 - inter;
        float iou = inter / uni;
        float cw = fmaxf(fmaxf(sx2, tx2) - fminf(sx1, tx1), 0.f);
        float chh = fmaxf(fmaxf(sy2, ty2) - fminf(sy1, ty1), 0.f);
        float areac = cw * chh;
        cg += -(iou - (areac - uni) / areac);
    }
    cls /= wsum;
    cb *= 0.125f;
    cg *= 0.125f;
    out[b * NQ + q] = cls + cb + cg + cost_mask + cost_dice + cost_proj;
}

__global__ __launch_bounds__(NT)
void argmin_kernel(float* __restrict__ out, int write_idx) {
    int b = blockIdx.x, t = threadIdx.x;
    float best = INFINITY;
    int bi = 0x7fffffff;
    for (int q = t; q < NQ; q += NT) {
        float v = out[b * NQ + q];
        if (v < best) { best = v; bi = q; }
    }
    #pragma unroll
    for (int off = 32; off > 0; off >>= 1) {
        float ov = __shfl_down(best, off, 64);
        int oi = __shfl_down(bi, off, 64);
        if (ov < best || (ov == best && oi < bi)) { best = ov; bi = oi; }
    }
    __shared__ float rv[4];
    __shared__ int ri[4];
    int wid = t >> 6, lane = t & 63;
    if (lane == 0) { rv[wid] = best; ri[wid] = bi; }
    __syncthreads();
    if (t == 0 && write_idx) {
        #pragma unroll
        for (int w = 1; w < 4; ++w) {
            if (rv[w] < best || (rv[w] == best && ri[w] < bi)) { best = rv[w]; bi = ri[w]; }
        }
        out[2 * NQ + b] = (float)bi;       // src_ind
        out[2 * NQ + 2 + b] = 0.f;         // tgt_ind
    }
}

extern "C" void kernel_launch(void* const* d_in, const int* in_sizes, int n_in,
                              void* d_out, int out_size, void* d_ws, size_t ws_size,
                              hipStream_t stream) {
    const float* logits = (const float*)d_in[0];
    const float* boxes  = (const float*)d_in[1];
    const float* masks  = (const float*)d_in[2];
    const float* tmask  = (const float*)d_in[3];
    const float* tbox   = (const float*)d_in[4];
    const int*   tvalid = (const int*)d_in[5];
    const unsigned char* vpad = (const unsigned char*)d_in[6];
    float* out = (float*)d_out;
    float* ws  = (float*)d_ws;

    targets_kernel<<<NBF, NT, 0, stream>>>(tmask, ws);
    partial_kernel<<<NBF * NQ, NT, 0, stream>>>(masks, tmask, vpad, ws, ws + WS_PART);
    combine_kernel<<<(2 * NQ + NT - 1) / NT, NT, 0, stream>>>(logits, boxes, tbox,
                                                              tvalid, ws, out);
    int write_idx = (out_size >= 2 * NQ + 4) ? 1 : 0;
    argmin_kernel<<<2, NT, 0, stream>>>(out, write_idx);
}